// Round 3
// baseline (123.183 us; speedup 1.0000x reference)
//
#include <hip/hip_runtime.h>
#include <hip/hip_fp16.h>
#include <math.h>

#define BATCH 16384
#define MAXF 32
#define NFEAT 768
#define FT_OUT 1024
#define CHUNK 32                      // columns per chunk; e5m2 -> 32-B LDS row
#define NCHUNK (FT_OUT / CHUNK)       // 32 chunks
#define GROUPS 32                     // 1024 blocks = 4/CU, exactly 8 iters each
#define CH_BYTES (NFEAT * CHUNK)      // 24576 B = 24 KiB

// compile-time component select for unrolled loops (f is a constant after unroll)
#define GET4(a, f) (((f) & 3) == 0 ? (a)[(f) >> 2].x : \
                    ((f) & 3) == 1 ? (a)[(f) >> 2].y : \
                    ((f) & 3) == 2 ? (a)[(f) >> 2].z : (a)[(f) >> 2].w)

typedef unsigned int uint_t;

// ---- e5m2 (bf8) helpers -------------------------------------------------
// e5m2 is f16 truncated to its top byte: f16 = byte << 8 EXACTLY. Encode:
// RNE-round the f16 low byte away. (R14/R15 verified: absmax unchanged vs f16.)
__device__ __forceinline__ uint_t rne_e5m2(float w) {
    unsigned short h = __half_as_ushort(__float2half(w));   // f32->f16 RNE
    unsigned short t = (unsigned short)(h + 0x7F + ((h >> 8) & 1)); // RNE to byte
    return (uint_t)(t >> 8) & 0xFFu;
}
__device__ __forceinline__ uint_t pack4_e5m2(float4 f) {
    return rne_e5m2(f.x) | (rne_e5m2(f.y) << 8) |
           (rne_e5m2(f.z) << 16) | (rne_e5m2(f.w) << 24);
}
// Decode 4 bf8 (one dword) -> two half2, fused with the accumulate.
// 1 v_perm per 2 cols; q passed as both perm srcs so the src byte-numbering
// convention is irrelevant (sel uses 0x00-0x03 picks + 0x0C = const 0).
__device__ __forceinline__ void fma4_bf8(uint_t q, __half2 v2,
                                         __half2& a0, __half2& a1) {
    uint_t lo = __builtin_amdgcn_perm(q, q, 0x010C000Cu); // b0<<8, b1<<8
    uint_t hi = __builtin_amdgcn_perm(q, q, 0x030C020Cu); // b2<<8, b3<<8
    a0 = __hfma2(*reinterpret_cast<__half2*>(&lo), v2, a0);
    a1 = __hfma2(*reinterpret_cast<__half2*>(&hi), v2, a1);
}

// Hard-won invariants (R1-R13):
//  - static __shared__ only (dynamic LDS breaks reg promotion; R7/R11)
//  - NO __threadfence (evicts L2-resident table; R8 vs R9)
//  - plain stores, no atomics/memset; no L2-side gather assist (R6/R13)
// R14/R15 lessons:
//  - e5m2 halves LDS bytes exactly as modeled (instrs & conflicts tracked
//    predictions both rounds) -- the FORMAT is good.
//  - 16-col/lane (uint4) layout blows the live set; allocator either
//    remats at 64 VGPR (R14) or collapses to 44 VGPR serial code (R15).
//  - the si[8]/ni[8]/vv[8] preload + hoisted f32 epilogue constants ARE the
//    register-pressure floor that forces the proven 80-VGPR ILP schedule.
// R16: R0's exact shape (4 lanes/sample, 8 cols/lane, preload, hoisted
// consts) + e5m2 table. Lane reads uint2 (ds_read_b64): same instr count as
// R0, half the bytes/instr. Wall model: 8.2k instr/CU x ~8 cyc => ~66-80k
// cyc => 28-34us main (R0: 114.5k cyc / 47.7us). Added perm VALU ~+16k
// cyc/SIMD on R0's calibrated 52k => ~65k, stays under the LDS wall.
__global__ __launch_bounds__(256, 4) void nnboard_main(
    const float* __restrict__ values,
    const int*   __restrict__ stm_idx,
    const int*   __restrict__ nstm_idx,
    const float* __restrict__ ft_w,
    const float* __restrict__ ft_b,
    const float* __restrict__ out_w,
    float*       __restrict__ partials)   // [NCHUNK][BATCH]
{
    __shared__ __align__(16) unsigned char s_tab[CH_BYTES]; // 24 KiB, 32-B rows

    const int tid = threadIdx.x;
    const int c = blockIdx.x % NCHUNK;    // chunk: cols [32c, 32c+32)
    const int g = blockIdx.x / NCHUNK;    // stripe 0..31
    const __half2 zero2 = __float2half2_rn(0.f);

    // ---- stage chunk c from fp32 ft_w as e5m2: 8 lanes/row, 128-B coalesced
    // write: bank (r*8 + lane8) % 32 -> tids 0..31 cover 32 banks, conflict-free
    {
        const int lane8 = tid & 7;
        const int rbase = tid >> 3;
        #pragma unroll
        for (int k = 0; k < NFEAT / 32; ++k) {
            const int r = k * 32 + rbase;
            const float4 f = *(const float4*)(ft_w + (size_t)r * FT_OUT + c * CHUNK + lane8 * 4);
            *(uint_t*)(s_tab + r * CHUNK + lane8 * 4) = pack4_e5m2(f);
        }
    }
    __syncthreads();

    const int grp = tid >> 2;             // 0..63 : sample slot per iteration
    const int j   = tid & 3;              // lane within sample (owns 8 cols)
    const int col0 = c * CHUNK + j * 8;
    const unsigned char* my_tab = s_tab + j * 8; // + row*CHUNK per gathered row

    // hoisted epilogue constants: 24 f32 regs -- part of the live-set floor
    const float4 bia0 = *(const float4*)(ft_b + col0);
    const float4 bia1 = *(const float4*)(ft_b + col0 + 4);
    const float4 ws0  = *(const float4*)(out_w + col0);
    const float4 ws1  = *(const float4*)(out_w + col0 + 4);
    const float4 wn0  = *(const float4*)(out_w + FT_OUT + col0);
    const float4 wn1  = *(const float4*)(out_w + FT_OUT + col0 + 4);

    for (int it = g; it < BATCH / 64; it += GROUPS) {   // exactly 8 iters
        const int b = it * 64 + grp;

        const int4*   sp = (const int4*)(stm_idx + b * MAXF);
        const int4*   np = (const int4*)(nstm_idx + b * MAXF);
        const float4* vp = (const float4*)(values + b * MAXF);
        int4 si[8], ni[8];
        float4 vv[8];
        #pragma unroll
        for (int k = 0; k < 8; ++k) { si[k] = sp[k]; ni[k] = np[k]; vv[k] = vp[k]; }

        __half2 accs[4] = {zero2, zero2, zero2, zero2};
        __half2 accn[4] = {zero2, zero2, zero2, zero2};

        #pragma unroll
        for (int f = 0; f < MAXF; ++f) {
            const int is = GET4(si, f);
            const int in = GET4(ni, f);
            const __half2 v2 = __float2half2_rn(GET4(vv, f));
            const uint2 qs = *(const uint2*)(my_tab + is * CHUNK);
            const uint2 qn = *(const uint2*)(my_tab + in * CHUNK);
            fma4_bf8(qs.x, v2, accs[0], accs[1]);
            fma4_bf8(qs.y, v2, accs[2], accs[3]);
            fma4_bf8(qn.x, v2, accn[0], accn[1]);
            fma4_bf8(qn.y, v2, accn[2], accn[3]);
        }

        float p = 0.f;
        {
            const float2 f0 = __half22float2(accs[0]);
            const float2 f1 = __half22float2(accs[1]);
            const float2 f2 = __half22float2(accs[2]);
            const float2 f3 = __half22float2(accs[3]);
            const float2 g0 = __half22float2(accn[0]);
            const float2 g1 = __half22float2(accn[1]);
            const float2 g2 = __half22float2(accn[2]);
            const float2 g3 = __half22float2(accn[3]);
            auto clip = [](float x) { return fminf(fmaxf(x, 0.f), 1.f); };
            p = fmaf(clip(f0.x + bia0.x), ws0.x, p);
            p = fmaf(clip(f0.y + bia0.y), ws0.y, p);
            p = fmaf(clip(f1.x + bia0.z), ws0.z, p);
            p = fmaf(clip(f1.y + bia0.w), ws0.w, p);
            p = fmaf(clip(f2.x + bia1.x), ws1.x, p);
            p = fmaf(clip(f2.y + bia1.y), ws1.y, p);
            p = fmaf(clip(f3.x + bia1.z), ws1.z, p);
            p = fmaf(clip(f3.y + bia1.w), ws1.w, p);
            p = fmaf(clip(g0.x + bia0.x), wn0.x, p);
            p = fmaf(clip(g0.y + bia0.y), wn0.y, p);
            p = fmaf(clip(g1.x + bia0.z), wn0.z, p);
            p = fmaf(clip(g1.y + bia0.w), wn0.w, p);
            p = fmaf(clip(g2.x + bia1.x), wn1.x, p);
            p = fmaf(clip(g2.y + bia1.y), wn1.y, p);
            p = fmaf(clip(g3.x + bia1.z), wn1.z, p);
            p = fmaf(clip(g3.y + bia1.w), wn1.w, p);
        }

        // reduce 4 lanes of the sample group (tid = grp*4 + j, contiguous)
        p += __shfl_down(p, 1, 64);
        p += __shfl_down(p, 2, 64);
        if (j == 0) partials[c * BATCH + b] = p;   // plain store, 16 lanes/wave
    }
}

// Epilogue: sum 32 chunk-partials per sample (coalesced: stride-BATCH rows,
// consecutive samples -> consecutive addresses), + out_b, sigmoid.
__global__ __launch_bounds__(256) void reduce_sigmoid_kernel(
    const float* __restrict__ partials,
    const float* __restrict__ out_b,
    float* __restrict__ out)
{
    const int i = blockIdx.x * 256 + threadIdx.x;
    float s = out_b[0];
    #pragma unroll
    for (int k = 0; k < NCHUNK; ++k)
        s += partials[k * BATCH + i];
    out[i] = 1.f / (1.f + expf(-s));
}

extern "C" void kernel_launch(void* const* d_in, const int* in_sizes, int n_in,
                              void* d_out, int out_size, void* d_ws, size_t ws_size,
                              hipStream_t stream) {
    const float* values   = (const float*)d_in[0];
    const int*   stm_idx  = (const int*)d_in[1];
    const int*   nstm_idx = (const int*)d_in[2];
    const float* ft_w     = (const float*)d_in[3];
    const float* ft_b     = (const float*)d_in[4];
    const float* out_w    = (const float*)d_in[5];
    const float* out_b    = (const float*)d_in[6];
    float*       out      = (float*)d_out;

    float* partials = (float*)d_ws;   // [32][16384] f32 = 2 MB, fully overwritten

    nnboard_main<<<NCHUNK * GROUPS, 256, 0, stream>>>(
        values, stm_idx, nstm_idx, ft_w, ft_b, out_w, partials);
    reduce_sigmoid_kernel<<<BATCH / 256, 256, 0, stream>>>(partials, out_b, out);
}

// Round 4
// 119.337 us; speedup vs baseline: 1.0322x; 1.0322x over previous
//
#include <hip/hip_runtime.h>
#include <hip/hip_fp16.h>
#include <math.h>

#define BATCH 16384
#define MAXF 32
#define NFEAT 768
#define FT_OUT 1024
#define CHUNK 32                      // columns per chunk (64-B LDS row, f16)
#define NCHUNK (FT_OUT / CHUNK)       // 32 chunks
#define GROUPS 24                     // stripes per chunk -> 768 blocks = 3/CU
#define CH_HALVES (NFEAT * CHUNK)     // 24576 halves = 48 KiB

// compile-time component select for unrolled loops (f is a constant after unroll)
#define GET4(a, f) (((f) & 3) == 0 ? (a)[(f) >> 2].x : \
                    ((f) & 3) == 1 ? (a)[(f) >> 2].y : \
                    ((f) & 3) == 2 ? (a)[(f) >> 2].z : (a)[(f) >> 2].w)

typedef unsigned int uint_t;

// Main: stage fp32 chunk -> f16 LDS, stream samples, write per-chunk partial
// logits with PLAIN STORES (each (chunk,sample) pair written exactly once).
//
// Hard-won invariants (R1-R13):
//  - static __shared__ only: dynamic LDS breaks array reg-promotion (R7/R11).
//  - NO __threadfence: evicts the L2-resident table mid-run (R8 vs R9).
//  - 48 KiB / 3 blocks/CU is the occupancy sweet spot (R5/R7/R11/R12).
//  - no L2-side gather assist (R6, R13).
// R14-R16 lessons (e5m2 axis, abandoned):
//  - e5m2 halves LDS traffic exactly as modeled, BUT all three layouts
//    collapsed the allocator out of the proven 80-VGPR ILP schedule
//    (remat bloat at 64 VGPR, or serial 44-VGPR code). The uint4 qs/qn
//    live pairs appear to be what FORCES the good schedule. Do not
//    perturb the inner-loop register shape.
// R17: R0 verbatim + row-indexed XOR bank swizzle. Old layout: start bank
// = 16*(r&1) + 4j -> per j-group 16 lanes on 2 of 8 four-bank spans
// (~8-way, measured +4.5 cyc/instr conflict). New: 16-B unit j of row r
// stored at physical unit j ^ ((r>>1)&3) -> start bank sweeps all 8 spans
// over r mod 8 -> ~2 lanes/span = free regime (m136). Write side uses the
// matching even XOR on 8-B staging units (pairs preserved -> 16-B reads
// stay contiguous). Wall model: 8.2k instr/CU x ~9 cyc ~= 74k cyc
// => predict main 31-37 us (was 47.7 at 12.5 cyc eff).
__global__ __launch_bounds__(256, 3) void nnboard_main(
    const float* __restrict__ values,
    const int*   __restrict__ stm_idx,
    const int*   __restrict__ nstm_idx,
    const float* __restrict__ ft_w,
    const float* __restrict__ ft_b,
    const float* __restrict__ out_w,
    float*       __restrict__ partials)   // [NCHUNK][BATCH]
{
    __shared__ __half s_tab[CH_HALVES];   // 48 KiB, row stride 32 halves (64 B)

    const int tid = threadIdx.x;
    const int c = blockIdx.x % NCHUNK;    // chunk: cols [32c, 32c+32)
    const int g = blockIdx.x / NCHUNK;    // stripe 0..23
    const __half2 zero2 = __float2half2_rn(0.f);

    // ---- stage chunk c directly from fp32 ft_w: 8 lanes/row, 128-B coalesced
    // 8-B unit lane8 goes to physical unit lane8 ^ (((r>>1)&3)<<1): even XOR
    // keeps 16-B pairs contiguous for the b128 reads below.
    {
        const int lane8 = tid & 7;
        const int rbase = tid >> 3;
        #pragma unroll
        for (int k = 0; k < NFEAT / 32; ++k) {
            const int r = k * 32 + rbase;
            const float4 f = *(const float4*)(ft_w + (size_t)r * FT_OUT + c * CHUNK + lane8 * 4);
            __half2 h0 = __floats2half2_rn(f.x, f.y);
            __half2 h1 = __floats2half2_rn(f.z, f.w);
            uint2 u;
            u.x = *reinterpret_cast<uint_t*>(&h0);
            u.y = *reinterpret_cast<uint_t*>(&h1);
            const int su = lane8 ^ (((r >> 1) & 3) << 1);   // swizzled 8-B unit
            *(uint2*)(s_tab + r * CHUNK + su * 4) = u;
        }
    }
    __syncthreads();

    const int grp = tid >> 2;             // 0..63 : sample slot per iteration
    const int j   = tid & 3;              // lane within sample (owns 8 cols)
    const int col0 = c * CHUNK + j * 8;

    const float4 bia0 = *(const float4*)(ft_b + col0);
    const float4 bia1 = *(const float4*)(ft_b + col0 + 4);
    const float4 ws0  = *(const float4*)(out_w + col0);
    const float4 ws1  = *(const float4*)(out_w + col0 + 4);
    const float4 wn0  = *(const float4*)(out_w + FT_OUT + col0);
    const float4 wn1  = *(const float4*)(out_w + FT_OUT + col0 + 4);

    for (int it = g; it < BATCH / 64; it += GROUPS) {
        const int b = it * 64 + grp;

        const int4*   sp = (const int4*)(stm_idx + b * MAXF);
        const int4*   np = (const int4*)(nstm_idx + b * MAXF);
        const float4* vp = (const float4*)(values + b * MAXF);
        int4 si[8], ni[8];
        float4 vv[8];
        #pragma unroll
        for (int k = 0; k < 8; ++k) { si[k] = sp[k]; ni[k] = np[k]; vv[k] = vp[k]; }

        __half2 accs[4] = {zero2, zero2, zero2, zero2};
        __half2 accn[4] = {zero2, zero2, zero2, zero2};

        #pragma unroll
        for (int f = 0; f < MAXF; ++f) {
            const int is = GET4(si, f);
            const int in = GET4(ni, f);
            const __half2 v2 = __float2half2_rn(GET4(vv, f));
            // swizzled read: 16-B unit j of row r lives at unit j^((r>>1)&3)
            const int us = (j ^ ((is >> 1) & 3)) * 8;       // halves offset
            const int un = (j ^ ((in >> 1) & 3)) * 8;
            const uint4 qs = *(const uint4*)(s_tab + is * CHUNK + us);
            const uint4 qn = *(const uint4*)(s_tab + in * CHUNK + un);
            accs[0] = __hfma2(*(const __half2*)&qs.x, v2, accs[0]);
            accs[1] = __hfma2(*(const __half2*)&qs.y, v2, accs[1]);
            accs[2] = __hfma2(*(const __half2*)&qs.z, v2, accs[2]);
            accs[3] = __hfma2(*(const __half2*)&qs.w, v2, accs[3]);
            accn[0] = __hfma2(*(const __half2*)&qn.x, v2, accn[0]);
            accn[1] = __hfma2(*(const __half2*)&qn.y, v2, accn[1]);
            accn[2] = __hfma2(*(const __half2*)&qn.z, v2, accn[2]);
            accn[3] = __hfma2(*(const __half2*)&qn.w, v2, accn[3]);
        }

        float p = 0.f;
        {
            const float2 f0 = __half22float2(accs[0]);
            const float2 f1 = __half22float2(accs[1]);
            const float2 f2 = __half22float2(accs[2]);
            const float2 f3 = __half22float2(accs[3]);
            const float2 g0 = __half22float2(accn[0]);
            const float2 g1 = __half22float2(accn[1]);
            const float2 g2 = __half22float2(accn[2]);
            const float2 g3 = __half22float2(accn[3]);
            auto clip = [](float x) { return fminf(fmaxf(x, 0.f), 1.f); };
            p = fmaf(clip(f0.x + bia0.x), ws0.x, p);
            p = fmaf(clip(f0.y + bia0.y), ws0.y, p);
            p = fmaf(clip(f1.x + bia0.z), ws0.z, p);
            p = fmaf(clip(f1.y + bia0.w), ws0.w, p);
            p = fmaf(clip(f2.x + bia1.x), ws1.x, p);
            p = fmaf(clip(f2.y + bia1.y), ws1.y, p);
            p = fmaf(clip(f3.x + bia1.z), ws1.z, p);
            p = fmaf(clip(f3.y + bia1.w), ws1.w, p);
            p = fmaf(clip(g0.x + bia0.x), wn0.x, p);
            p = fmaf(clip(g0.y + bia0.y), wn0.y, p);
            p = fmaf(clip(g1.x + bia0.z), wn0.z, p);
            p = fmaf(clip(g1.y + bia0.w), wn0.w, p);
            p = fmaf(clip(g2.x + bia1.x), wn1.x, p);
            p = fmaf(clip(g2.y + bia1.y), wn1.y, p);
            p = fmaf(clip(g3.x + bia1.z), wn1.z, p);
            p = fmaf(clip(g3.y + bia1.w), wn1.w, p);
        }

        // reduce 4 lanes of the sample group (tid = grp*4 + j, contiguous)
        p += __shfl_down(p, 1, 64);
        p += __shfl_down(p, 2, 64);
        if (j == 0) partials[c * BATCH + b] = p;   // plain store, 16 lanes/wave
    }
}

// Epilogue: sum 32 chunk-partials per sample (coalesced: stride-BATCH rows,
// consecutive samples -> consecutive addresses), + out_b, sigmoid.
__global__ __launch_bounds__(256) void reduce_sigmoid_kernel(
    const float* __restrict__ partials,
    const float* __restrict__ out_b,
    float* __restrict__ out)
{
    const int i = blockIdx.x * 256 + threadIdx.x;
    float s = out_b[0];
    #pragma unroll
    for (int k = 0; k < NCHUNK; ++k)
        s += partials[k * BATCH + i];
    out[i] = 1.f / (1.f + expf(-s));
}

extern "C" void kernel_launch(void* const* d_in, const int* in_sizes, int n_in,
                              void* d_out, int out_size, void* d_ws, size_t ws_size,
                              hipStream_t stream) {
    const float* values   = (const float*)d_in[0];
    const int*   stm_idx  = (const int*)d_in[1];
    const int*   nstm_idx = (const int*)d_in[2];
    const float* ft_w     = (const float*)d_in[3];
    const float* ft_b     = (const float*)d_in[4];
    const float* out_w    = (const float*)d_in[5];
    const float* out_b    = (const float*)d_in[6];
    float*       out      = (float*)d_out;

    float* partials = (float*)d_ws;   // [32][16384] f32 = 2 MB, fully overwritten

    nnboard_main<<<NCHUNK * GROUPS, 256, 0, stream>>>(
        values, stm_idx, nstm_idx, ft_w, ft_b, out_w, partials);
    reduce_sigmoid_kernel<<<BATCH / 256, 256, 0, stream>>>(partials, out_b, out);
}